// Round 1
// baseline (7111.503 us; speedup 1.0000x reference)
//
#include <hip/hip_runtime.h>
#include <stdint.h>

#define TPB 512

constexpr int Bb   = 8;    // batch
constexpr int Vv   = 200;  // vertices
constexpr int Tt   = 128;  // time
constexpr int CIN  = 128;  // concat channels
constexpr int COUT = 64;   // K_HEADS * D_HEAD

// bf16 helpers (manual RNE pack, shift unpack)
__device__ __forceinline__ unsigned short f2bf(float f) {
    union { float f; unsigned u; } x; x.f = f;
    unsigned r = x.u + 0x7fffu + ((x.u >> 16) & 1u);
    return (unsigned short)(r >> 16);
}
__device__ __forceinline__ float bflo(unsigned u) {
    union { unsigned u; float f; } x; x.u = u << 16; return x.f;
}
__device__ __forceinline__ float bfhi(unsigned u) {
    union { unsigned u; float f; } x; x.u = u & 0xffff0000u; return x.f;
}

// One block per (b, v). LDS arena (64 KB):
//   [0, 49152)      qkv  bf16 [3][128 t][64 o]   (t-major: k/v row = one b128 read)
//   [49152, 65536)  xtq  f32  [128 c][32 t]      (projection staging, per t-quarter)
//   [49152, 65536)  ot   bf16 [128 t][64 i]      (attention output, reuses xtq)
__global__ __launch_bounds__(TPB, 4)
void tatt_fused(const float* __restrict__ x, const float* __restrict__ tem,
                const float* __restrict__ Wq, const float* __restrict__ bq,
                const float* __restrict__ Wk, const float* __restrict__ bk,
                const float* __restrict__ Wv, const float* __restrict__ bv,
                const float* __restrict__ Wo, const float* __restrict__ bo,
                float* __restrict__ out)
{
    __shared__ __align__(16) unsigned char smem[65536];
    unsigned short* qkv = (unsigned short*)smem;           // [3][128][64] bf16
    float*          xtq = (float*)(smem + 49152);          // [128][32] f32
    unsigned short* ot  = (unsigned short*)(smem + 49152); // [128][64] bf16

    const int tid = threadIdx.x;
    const int bv_ = blockIdx.x;
    const int b = bv_ / Vv, v = bv_ % Vv;

    const float* Wp[3] = {Wq, Wk, Wv};
    const float* bp[3] = {bq, bk, bv};

    // ---------------- QKV projection, 4 t-quarters ----------------
    const int og = tid >> 5;   // 0..15 -> 4 output rows each
    const int tl = tid & 31;   // 0..31 -> local t
    for (int tq = 0; tq < 4; ++tq) {
        __syncthreads();  // protect xtq from previous quarter's readers
        // stage xt quarter: rows c<64 from x, c>=64 from tem; row = 32 floats
        for (int i = tid; i < 1024; i += TPB) {
            int c = i >> 3, q4 = i & 7;
            const float* src = (c < 64 ? x : tem)
                + ((b * 64 + (c & 63)) * Vv + v) * Tt + tq * 32 + q4 * 4;
            *(float4*)(xtq + c * 32 + q4 * 4) = *(const float4*)src;
        }
        __syncthreads();
        const int t = tq * 32 + tl;
        #pragma unroll
        for (int p = 0; p < 3; ++p) {
            const float* W0 = Wp[p] + (og * 4 + 0) * CIN;
            const float* W1 = Wp[p] + (og * 4 + 1) * CIN;
            const float* W2 = Wp[p] + (og * 4 + 2) * CIN;
            const float* W3 = Wp[p] + (og * 4 + 3) * CIN;
            float a0 = bp[p][og * 4 + 0];
            float a1 = bp[p][og * 4 + 1];
            float a2 = bp[p][og * 4 + 2];
            float a3 = bp[p][og * 4 + 3];
            for (int cb = 0; cb < 32; ++cb) {
                float x0 = xtq[(cb * 4 + 0) * 32 + tl];  // bank = tl%32: 2-way, free
                float x1 = xtq[(cb * 4 + 1) * 32 + tl];
                float x2 = xtq[(cb * 4 + 2) * 32 + tl];
                float x3 = xtq[(cb * 4 + 3) * 32 + tl];
                float4 w;
                w = *(const float4*)(W0 + cb * 4); a0 += w.x*x0 + w.y*x1 + w.z*x2 + w.w*x3;
                w = *(const float4*)(W1 + cb * 4); a1 += w.x*x0 + w.y*x1 + w.z*x2 + w.w*x3;
                w = *(const float4*)(W2 + cb * 4); a2 += w.x*x0 + w.y*x1 + w.z*x2 + w.w*x3;
                w = *(const float4*)(W3 + cb * 4); a3 += w.x*x0 + w.y*x1 + w.z*x2 + w.w*x3;
            }
            ushort4 st;
            st.x = f2bf(a0); st.y = f2bf(a1); st.z = f2bf(a2); st.w = f2bf(a3);
            *(ushort4*)(qkv + (p * Tt + t) * COUT + og * 4) = st;
        }
    }
    __syncthreads();  // QKV visible; xtq dead -> ot region safe

    // ---------------- causal attention: 4 heads/pass x 2 ----------------
    // fold 1/sqrt(8) and log2(e) into q; fixed-reference softmax (scores are
    // bounded ~|3|, so exp2 never over/underflows; normalization divides out)
    const float QS = 1.44269504088896f * 0.35355339059327f;
    const int r  = tid & 127;
    const int hh = tid >> 7;          // 0..3
    const int smax = (r | 63) + 1;    // wave-uniform loop bound (rows grouped by wave)
    for (int hp = 0; hp < 2; ++hp) {
        const int head = hp * 4 + hh;
        uint4 qu = *(const uint4*)(qkv + r * COUT + head * 8);
        float q0 = bflo(qu.x)*QS, q1 = bfhi(qu.x)*QS, q2 = bflo(qu.y)*QS, q3 = bfhi(qu.y)*QS;
        float q4 = bflo(qu.z)*QS, q5 = bfhi(qu.z)*QS, q6 = bflo(qu.w)*QS, q7 = bfhi(qu.w)*QS;
        const unsigned short* kb = qkv + (1 * Tt) * COUT + head * 8;
        const unsigned short* vb = qkv + (2 * Tt) * COUT + head * 8;
        float l = 0.f;
        float a0=0.f,a1=0.f,a2=0.f,a3=0.f,a4=0.f,a5=0.f,a6=0.f,a7=0.f;
        for (int s = 0; s < smax; ++s) {
            uint4 ku = *(const uint4*)(kb + s * COUT);  // wave-uniform addr: broadcast
            uint4 vu = *(const uint4*)(vb + s * COUT);
            float d = q0*bflo(ku.x) + q1*bfhi(ku.x) + q2*bflo(ku.y) + q3*bfhi(ku.y)
                    + q4*bflo(ku.z) + q5*bfhi(ku.z) + q6*bflo(ku.w) + q7*bfhi(ku.w);
            float p = __builtin_amdgcn_exp2f(d);
            p = (s <= r) ? p : 0.0f;                    // causal mask
            l += p;
            a0 += p * bflo(vu.x); a1 += p * bfhi(vu.x);
            a2 += p * bflo(vu.y); a3 += p * bfhi(vu.y);
            a4 += p * bflo(vu.z); a5 += p * bfhi(vu.z);
            a6 += p * bflo(vu.w); a7 += p * bfhi(vu.w);
        }
        float rl = __builtin_amdgcn_rcpf(l);
        uint4 st;
        st.x = (unsigned)f2bf(a0 * rl) | ((unsigned)f2bf(a1 * rl) << 16);
        st.y = (unsigned)f2bf(a2 * rl) | ((unsigned)f2bf(a3 * rl) << 16);
        st.z = (unsigned)f2bf(a4 * rl) | ((unsigned)f2bf(a5 * rl) << 16);
        st.w = (unsigned)f2bf(a6 * rl) | ((unsigned)f2bf(a7 * rl) << 16);
        *(uint4*)(ot + r * COUT + head * 8) = st;
    }
    __syncthreads();

    // ---------------- output projection + bias + relu ----------------
    const int o16 = (tid >> 7) * 16;  // 16 output channels per thread
    const int t   = tid & 127;
    float acc[16];
    #pragma unroll
    for (int oi = 0; oi < 16; ++oi) acc[oi] = bo[o16 + oi];
    for (int cb8 = 0; cb8 < 8; ++cb8) {
        int cb = (cb8 + t) & 7;  // lane-rotated chunk order: spreads LDS banks 8-way
        uint4 ou = *(const uint4*)(ot + t * COUT + cb * 8);
        float f0 = bflo(ou.x), f1 = bfhi(ou.x), f2 = bflo(ou.y), f3 = bfhi(ou.y);
        float f4 = bflo(ou.z), f5 = bfhi(ou.z), f6 = bflo(ou.w), f7 = bfhi(ou.w);
        #pragma unroll
        for (int oi = 0; oi < 16; ++oi) {
            const float* wr = Wo + (o16 + oi) * COUT + cb * 8;
            float4 w0 = *(const float4*)(wr);
            float4 w1 = *(const float4*)(wr + 4);
            acc[oi] += w0.x*f0 + w0.y*f1 + w0.z*f2 + w0.w*f3
                     + w1.x*f4 + w1.y*f5 + w1.z*f6 + w1.w*f7;
        }
    }
    #pragma unroll
    for (int oi = 0; oi < 16; ++oi) {
        float r_ = acc[oi] > 0.f ? acc[oi] : 0.f;
        out[((b * COUT + o16 + oi) * Vv + v) * Tt + t] = r_;  // lanes: consecutive t -> coalesced
    }
}

extern "C" void kernel_launch(void* const* d_in, const int* in_sizes, int n_in,
                              void* d_out, int out_size, void* d_ws, size_t ws_size,
                              hipStream_t stream) {
    (void)in_sizes; (void)n_in; (void)d_ws; (void)ws_size; (void)out_size;
    const float* x   = (const float*)d_in[0];
    const float* tem = (const float*)d_in[1];
    const float* Wq  = (const float*)d_in[2];
    const float* bq  = (const float*)d_in[3];
    const float* Wk  = (const float*)d_in[4];
    const float* bk  = (const float*)d_in[5];
    const float* Wv  = (const float*)d_in[6];
    const float* bv  = (const float*)d_in[7];
    const float* Wo  = (const float*)d_in[8];
    const float* bo  = (const float*)d_in[9];
    float* out = (float*)d_out;
    tatt_fused<<<dim3(Bb * Vv), dim3(TPB), 0, stream>>>(
        x, tem, Wq, bq, Wk, bk, Wv, bv, Wo, bo, out);
}

// Round 2
// 373.422 us; speedup vs baseline: 19.0441x; 19.0441x over previous
//
#include <hip/hip_runtime.h>
#include <stdint.h>

#define TPB 512

constexpr int Bb   = 8;    // batch
constexpr int Vv   = 200;  // vertices
constexpr int Tt   = 128;  // time
constexpr int CIN  = 128;  // concat channels
constexpr int COUT = 64;   // K_HEADS * D_HEAD

typedef __attribute__((ext_vector_type(8))) short bf16x8;
typedef __attribute__((ext_vector_type(4))) float f32x4;

// bf16 helpers (manual RNE pack, shift unpack)
__device__ __forceinline__ unsigned short f2bf(float f) {
    union { float f; unsigned u; } x; x.f = f;
    unsigned r = x.u + 0x7fffu + ((x.u >> 16) & 1u);
    return (unsigned short)(r >> 16);
}
__device__ __forceinline__ float bflo(unsigned u) {
    union { unsigned u; float f; } x; x.u = u << 16; return x.f;
}
__device__ __forceinline__ float bfhi(unsigned u) {
    union { unsigned u; float f; } x; x.u = u & 0xffff0000u; return x.f;
}

// ---- prep: convert W's to bf16 into d_ws (same work every launch) ----
// ws layout (ushort): [0,8192) Wq [8192,16384) Wk [16384,24576) Wv [24576,28672) Wo
__global__ void prep_w(const float* __restrict__ Wq, const float* __restrict__ Wk,
                       const float* __restrict__ Wv, const float* __restrict__ Wo,
                       unsigned short* __restrict__ ws) {
    int i = blockIdx.x * 256 + threadIdx.x;  // 28672 total
    float v;
    if (i < 8192)       v = Wq[i];
    else if (i < 16384) v = Wk[i - 8192];
    else if (i < 24576) v = Wv[i - 16384];
    else                v = Wo[i - 24576];
    ws[i] = f2bf(v);
}

// load q/k/v row (p,t) for head h from swizzled qkv LDS: returns 8 bf16 packed
// (o = h*8 .. h*8+7 in order). Half-chunks (8B) swizzled: phys_hc = hc ^ (t&15).
__device__ __forceinline__ uint4 ld_qkv(const unsigned short* qkv, int p, int t, int h) {
    const unsigned short* ptr = qkv + (p * Tt + t) * COUT + (((h << 1) ^ (t & 14)) << 2);
    uint4 u = *(const uint4*)ptr;
    if (t & 1) { uint4 s = make_uint4(u.z, u.w, u.x, u.y); return s; }
    return u;
}

// One block per (b, v). LDS (64 KB): qkv bf16 [3][128 t][64 o] swizzled @0 (48KB);
// xt bf16 [64 t][128 c] swizzled @49152 (16KB), reused as ot bf16 [128 t][64 i].
__global__ __launch_bounds__(TPB, 4)
void tatt_fused(const float* __restrict__ x, const float* __restrict__ tem,
                const float* __restrict__ bq, const float* __restrict__ bk,
                const float* __restrict__ bv, const float* __restrict__ bo,
                const unsigned short* __restrict__ ws,
                float* __restrict__ out)
{
    __shared__ __align__(16) unsigned char smem[65536];
    unsigned short* qkv = (unsigned short*)smem;            // [3][128][64] swizzled
    unsigned short* xt  = (unsigned short*)(smem + 49152);  // [64][128] swizzled
    unsigned short* ot  = (unsigned short*)(smem + 49152);  // [128][64] swizzled

    const int tid = threadIdx.x;
    const int w = tid >> 6, lane = tid & 63;
    const int lane15 = lane & 15, quad = lane >> 4;
    const int bv_ = blockIdx.x;
    const int b = bv_ / Vv, v = bv_ % Vv;

    const float* bpa[3] = {bq, bk, bv};

    // ---------------- phase 1: QKV projection via MFMA, two t-halves ----------------
    for (int half = 0; half < 2; ++half) {
        __syncthreads();  // xt region free (prev half's B-frag reads done)
        // stage xt half: [t 0..63][c 0..127] bf16, chunk-swizzled phys=(c>>3)^(t&15)
        #pragma unroll
        for (int k = 0; k < 4; ++k) {
            int idx = tid + k * TPB;          // 0..2047
            int c = idx & 127, t4 = idx >> 7; // t4 0..15
            const float* src = (c < 64 ? x : tem)
                + ((b * 64 + (c & 63)) * Vv + v) * Tt + half * 64 + t4 * 4;
            float4 f = *(const float4*)src;
            float fv[4] = {f.x, f.y, f.z, f.w};
            #pragma unroll
            for (int j = 0; j < 4; ++j) {
                int t = t4 * 4 + j;
                xt[t * CIN + (((c >> 3) ^ (t & 15)) << 3) + (c & 7)] = f2bf(fv[j]);
            }
        }
        __syncthreads();
        // 48 tiles (p,ot_,tt) of 16x16, 6 per wave, K=128 (4 MFMA each)
        #pragma unroll
        for (int j = 0; j < 6; ++j) {
            int tile = w * 6 + j;
            int p = tile >> 4, rem = tile & 15;
            int ot_ = rem & 3, tt = rem >> 2;
            f32x4 acc = {0.f, 0.f, 0.f, 0.f};
            const unsigned short* Wb = ws + p * 8192 + (ot_ * 16 + lane15) * CIN + quad * 8;
            const unsigned short* Bb = xt + (tt * 16 + lane15) * CIN;
            #pragma unroll
            for (int kc = 0; kc < 4; ++kc) {
                bf16x8 a = *(const bf16x8*)(Wb + kc * 32);
                int phys = (kc * 4 + quad) ^ lane15;
                bf16x8 bb = *(const bf16x8*)(Bb + phys * 8);
                acc = __builtin_amdgcn_mfma_f32_16x16x32_bf16(a, bb, acc, 0, 0, 0);
            }
            // bias + store to qkv (swizzled half-chunks)
            int obase = ot_ * 16 + quad * 4;
            float4 bias = *(const float4*)(bpa[p] + obase);
            int tg = half * 64 + tt * 16 + lane15;
            int phys_hc = ((obase >> 2) ^ lane15);
            ushort4 st;
            st.x = f2bf(acc[0] + bias.x); st.y = f2bf(acc[1] + bias.y);
            st.z = f2bf(acc[2] + bias.z); st.w = f2bf(acc[3] + bias.w);
            *(ushort4*)(qkv + (p * Tt + tg) * COUT + phys_hc * 4) = st;
        }
    }
    __syncthreads();  // qkv complete; xt dead -> ot region safe

    // ---------------- phase 2: causal attention (VALU), 4 heads/pass x 2 ----------------
    const float QS = 1.44269504088896f * 0.35355339059327f;  // log2(e)/sqrt(8)
    const int r  = tid & 127;
    const int hh = tid >> 7;          // 0..3
    const int smax = (r | 63) + 1;    // wave-uniform (rows grouped by wave)
    for (int hp = 0; hp < 2; ++hp) {
        const int head = hp * 4 + hh;
        uint4 qu = ld_qkv(qkv, 0, r, head);
        float q0 = bflo(qu.x)*QS, q1 = bfhi(qu.x)*QS, q2 = bflo(qu.y)*QS, q3 = bfhi(qu.y)*QS;
        float q4 = bflo(qu.z)*QS, q5 = bfhi(qu.z)*QS, q6 = bflo(qu.w)*QS, q7 = bfhi(qu.w)*QS;
        float l = 0.f;
        float a0=0.f,a1=0.f,a2=0.f,a3=0.f,a4=0.f,a5=0.f,a6=0.f,a7=0.f;
        for (int s = 0; s < smax; ++s) {
            uint4 ku = ld_qkv(qkv, 1, s, head);  // wave-uniform addr: broadcast
            uint4 vu = ld_qkv(qkv, 2, s, head);
            float d = q0*bflo(ku.x) + q1*bfhi(ku.x) + q2*bflo(ku.y) + q3*bfhi(ku.y)
                    + q4*bflo(ku.z) + q5*bfhi(ku.z) + q6*bflo(ku.w) + q7*bfhi(ku.w);
            float p = __builtin_amdgcn_exp2f(d);
            p = (s <= r) ? p : 0.0f;             // causal mask
            l += p;
            a0 += p * bflo(vu.x); a1 += p * bfhi(vu.x);
            a2 += p * bflo(vu.y); a3 += p * bfhi(vu.y);
            a4 += p * bflo(vu.z); a5 += p * bfhi(vu.z);
            a6 += p * bflo(vu.w); a7 += p * bfhi(vu.w);
        }
        float rl = __builtin_amdgcn_rcpf(l);
        uint4 st;
        st.x = (unsigned)f2bf(a0 * rl) | ((unsigned)f2bf(a1 * rl) << 16);
        st.y = (unsigned)f2bf(a2 * rl) | ((unsigned)f2bf(a3 * rl) << 16);
        st.z = (unsigned)f2bf(a4 * rl) | ((unsigned)f2bf(a5 * rl) << 16);
        st.w = (unsigned)f2bf(a6 * rl) | ((unsigned)f2bf(a7 * rl) << 16);
        // ot row r, chunk=head, phys = head ^ (r&7)
        *(uint4*)(ot + r * COUT + ((head ^ (r & 7)) << 3)) = st;
    }
    __syncthreads();

    // ---------------- phase 3: out-projection via MFMA + bias + relu ----------------
    {
        const int tt = w;  // wave w owns t-tile w (16 t), all 4 o-tiles
        #pragma unroll
        for (int ot_ = 0; ot_ < 4; ++ot_) {
            f32x4 acc = {0.f, 0.f, 0.f, 0.f};
            const unsigned short* Ab = ws + 24576 + (ot_ * 16 + lane15) * COUT + quad * 8;
            const unsigned short* Bb = ot + (tt * 16 + lane15) * COUT;
            #pragma unroll
            for (int kc = 0; kc < 2; ++kc) {
                bf16x8 a = *(const bf16x8*)(Ab + kc * 32);
                int phys = (kc * 4 + quad) ^ (lane15 & 7);
                bf16x8 bb = *(const bf16x8*)(Bb + phys * 8);
                acc = __builtin_amdgcn_mfma_f32_16x16x32_bf16(a, bb, acc, 0, 0, 0);
            }
            int obase = ot_ * 16 + quad * 4;
            float4 bias = *(const float4*)(bo + obase);
            int t = tt * 16 + lane15;
            float bb4[4] = {bias.x, bias.y, bias.z, bias.w};
            #pragma unroll
            for (int reg = 0; reg < 4; ++reg) {
                float val = acc[reg] + bb4[reg];
                val = val > 0.f ? val : 0.f;
                out[((b * COUT + obase + reg) * Vv + v) * Tt + t] = val;
            }
        }
    }
}

extern "C" void kernel_launch(void* const* d_in, const int* in_sizes, int n_in,
                              void* d_out, int out_size, void* d_ws, size_t ws_size,
                              hipStream_t stream) {
    (void)in_sizes; (void)n_in; (void)ws_size; (void)out_size;
    const float* x   = (const float*)d_in[0];
    const float* tem = (const float*)d_in[1];
    const float* Wq  = (const float*)d_in[2];
    const float* bq  = (const float*)d_in[3];
    const float* Wk  = (const float*)d_in[4];
    const float* bk  = (const float*)d_in[5];
    const float* Wv  = (const float*)d_in[6];
    const float* bv  = (const float*)d_in[7];
    const float* Wo  = (const float*)d_in[8];
    const float* bo  = (const float*)d_in[9];
    float* out = (float*)d_out;
    unsigned short* ws = (unsigned short*)d_ws;

    prep_w<<<dim3(112), dim3(256), 0, stream>>>(Wq, Wk, Wv, Wo, ws);
    tatt_fused<<<dim3(Bb * Vv), dim3(TPB), 0, stream>>>(
        x, tem, bq, bk, bv, bo, ws, out);
}

// Round 4
// 269.115 us; speedup vs baseline: 26.4255x; 1.3876x over previous
//
#include <hip/hip_runtime.h>
#include <stdint.h>

#define TPB 512

constexpr int Bb   = 8;    // batch
constexpr int Vv   = 200;  // vertices
constexpr int Tt   = 128;  // time
constexpr int CIN  = 128;  // concat channels
constexpr int COUT = 64;   // K_HEADS * D_HEAD

typedef __attribute__((ext_vector_type(8))) short bf16x8;
typedef __attribute__((ext_vector_type(4))) short short4v;
typedef __attribute__((ext_vector_type(4))) float f32x4;

// bf16 helpers (manual RNE)
__device__ __forceinline__ unsigned short f2bf(float f) {
    union { float f; unsigned u; } x; x.f = f;
    unsigned r = x.u + 0x7fffu + ((x.u >> 16) & 1u);
    return (unsigned short)(r >> 16);
}
// pack two floats -> two bf16 in one u32 (low = a), RNE
__device__ __forceinline__ unsigned pk2(float a, float b) {
    return (unsigned)f2bf(a) | ((unsigned)f2bf(b) << 16);
}

// 16x16x16 bf16 MFMA (K=16): B-layout (k=quad*4+j, n=lane&15) == C-layout of a
// prior MFMA transposed-in-place -> used for PV with zero cross-lane movement.
#if __has_builtin(__builtin_amdgcn_mfma_f32_16x16x16bf16_1k)
#define MFMA16(a, b, c) __builtin_amdgcn_mfma_f32_16x16x16bf16_1k(a, b, c, 0, 0, 0)
#else
__device__ __forceinline__ f32x4 mfma16_asm(short4v a, short4v b, f32x4 c) {
    f32x4 d;
    asm("v_mfma_f32_16x16x16_bf16 %0, %1, %2, %3" : "=v"(d) : "v"(a), "v"(b), "v"(c));
    return d;
}
#define MFMA16(a, b, c) mfma16_asm(a, b, c)
#endif

// ---- prep: convert W's to bf16 into d_ws (same work every launch) ----
// ws layout (ushort): [0,8192) Wq [8192,16384) Wk [16384,24576) Wv [24576,28672) Wo
__global__ void prep_w(const float* __restrict__ Wq, const float* __restrict__ Wk,
                       const float* __restrict__ Wv, const float* __restrict__ Wo,
                       unsigned short* __restrict__ ws) {
    int i = blockIdx.x * 256 + threadIdx.x;  // 28672 total
    float v;
    if (i < 8192)       v = Wq[i];
    else if (i < 16384) v = Wk[i - 8192];
    else if (i < 24576) v = Wv[i - 16384];
    else                v = Wo[i - 24576];
    ws[i] = f2bf(v);
}

// One block per (b, v). LDS (64 KB):
//   qk  bf16 Q[128][64] @0, K[128][64] @16384  (8B-chunk swizzle: phys_hc = hc ^ (t&14))
//   vt  bf16 VT[64 dg][128 s] @32768           (col swizzle: s_phys = s ^ (((dg>>2)&3)<<4))
//   xt  bf16 [64 t][128 c] @49152 (phase 1)  /  ot bf16 [128 t][64 i] @49152 (phase 2/3)
__global__ __launch_bounds__(TPB, 4)
void tatt_fused(const float* __restrict__ x, const float* __restrict__ tem,
                const float* __restrict__ bq, const float* __restrict__ bk,
                const float* __restrict__ bv, const float* __restrict__ bo,
                const unsigned short* __restrict__ ws,
                float* __restrict__ out)
{
    __shared__ __align__(16) unsigned char smem[65536];
    unsigned short* qk = (unsigned short*)smem;            // Q @0 (elts), K @8192 (elts)
    unsigned short* vt = (unsigned short*)(smem + 32768);  // VT [64][128]
    unsigned short* xt = (unsigned short*)(smem + 49152);
    unsigned short* ot = (unsigned short*)(smem + 49152);

    const int tid = threadIdx.x;
    const int w = tid >> 6, lane = tid & 63;
    const int l15 = lane & 15, qd = lane >> 4;
    const int b = blockIdx.x / Vv, v = blockIdx.x % Vv;
    const float QS = 1.44269504088896f * 0.35355339059327f;  // log2(e)/sqrt(8)

    const float* bpa[3] = {bq, bk, bv};

    // ---------------- phase 1: QKV projection via MFMA, two t-halves ----------------
    for (int half = 0; half < 2; ++half) {
        __syncthreads();  // xt free (prev half's B-frag reads done)
        #pragma unroll
        for (int k = 0; k < 4; ++k) {
            int idx = tid + k * TPB;           // 0..2047
            int c = idx & 127, t4 = idx >> 7;  // t4 0..15
            const float* src = (c < 64 ? x : tem)
                + ((b * 64 + (c & 63)) * Vv + v) * Tt + half * 64 + t4 * 4;
            float4 f = *(const float4*)src;
            float fv[4] = {f.x, f.y, f.z, f.w};
            #pragma unroll
            for (int j = 0; j < 4; ++j) {
                int t = t4 * 4 + j;
                xt[t * CIN + (((c >> 3) ^ (t & 15)) << 3) + (c & 7)] = f2bf(fv[j]);
            }
        }
        __syncthreads();
        // 48 tiles (p, ot_, tt) of 16x16, 6 per wave, K=128
        #pragma unroll
        for (int j = 0; j < 6; ++j) {
            int tile = w * 6 + j;
            int p = tile >> 4, rem = tile & 15;
            int ot_ = rem & 3, tt = rem >> 2;
            f32x4 acc = {0.f, 0.f, 0.f, 0.f};
            const unsigned short* Wb  = ws + p * 8192 + (ot_ * 16 + l15) * CIN + qd * 8;
            const unsigned short* Bbp = xt + (tt * 16 + l15) * CIN;
            #pragma unroll
            for (int kc = 0; kc < 4; ++kc) {
                bf16x8 a = *(const bf16x8*)(Wb + kc * 32);
                int phys = (kc * 4 + qd) ^ l15;
                bf16x8 bbv = *(const bf16x8*)(Bbp + phys * 8);
                acc = __builtin_amdgcn_mfma_f32_16x16x32_bf16(a, bbv, acc, 0, 0, 0);
            }
            int obase = ot_ * 16 + qd * 4;
            float4 bias = *(const float4*)(bpa[p] + obase);
            float bb4[4] = {bias.x, bias.y, bias.z, bias.w};
            int tg = half * 64 + tt * 16 + l15;
            if (p == 2) {
                // V stored transposed: VT[dg][t], column-swizzled by dg quad-group
                #pragma unroll
                for (int r = 0; r < 4; ++r) {
                    int dg = obase + r;
                    int tp = tg ^ ((((dg >> 2) & 3)) << 4);
                    vt[dg * 128 + tp] = f2bf(acc[r] + bb4[r]);
                }
            } else {
                // Q pre-scaled by log2(e)/sqrt(d); 8B-chunk swizzle ^(t&14) keeps
                // b128 (chunk-pair) frag reads adjacency-safe in phase 2
                float sc = (p == 0) ? QS : 1.0f;
                ushort4 st4;
                st4.x = f2bf((acc[0] + bb4[0]) * sc);
                st4.y = f2bf((acc[1] + bb4[1]) * sc);
                st4.z = f2bf((acc[2] + bb4[2]) * sc);
                st4.w = f2bf((acc[3] + bb4[3]) * sc);
                int phys = (obase >> 2) ^ (tg & 14);
                *(ushort4*)(qk + p * 8192 + tg * 64 + phys * 4) = st4;
            }
        }
    }
    __syncthreads();  // Q/K/VT complete; xt dead -> ot region safe

    // ---------------- phase 2: causal attention via MFMA, wave = head ----------------
    // S^T = K·Q^T (16x16x32, K-dim=8 real). C-layout: col=l15=t, row=qd*4+reg=s.
    // P^T (exp2, masked) is ALREADY in B-layout for 16x16x16 PV: O^T = V^T·P~^T.
    {
        const int h = w;
        // cache V A-frags: lane m=l15=d (valid <8), k=qd*4+j
        short4v vfrag[8];
        {
            int dg = h * 8 + l15;
            int swz = ((dg >> 2) & 3) << 4;
            #pragma unroll
            for (int st = 0; st < 8; ++st) {
                short4v f = {0, 0, 0, 0};
                if (l15 < 8) {
                    int sp = (st * 16 + qd * 4) ^ swz;
                    f = *(const short4v*)(vt + dg * 128 + sp);
                }
                vfrag[st] = f;
            }
        }
        bool dmask[4];
        #pragma unroll
        for (int r = 0; r < 4; ++r) dmask[r] = (qd * 4 + r) <= l15;  // diag: s<=t
        const int qkoff = ((h * 2) ^ (l15 & 14)) << 2;

        for (int tt = 0; tt < 8; ++tt) {
            bf16x8 qf = {0, 0, 0, 0, 0, 0, 0, 0};
            if (qd == 0) qf = *(const bf16x8*)(qk + (tt * 16 + l15) * 64 + qkoff);
            f32x4 o0 = {0.f, 0.f, 0.f, 0.f}, o1 = {0.f, 0.f, 0.f, 0.f};
            float lac = 0.f;
            #pragma unroll
            for (int st = 0; st < 8; ++st) {
                if (st <= tt) {  // causal tile skip (wave-uniform branch)
                    bf16x8 kf = {0, 0, 0, 0, 0, 0, 0, 0};
                    if (qd == 0) kf = *(const bf16x8*)(qk + 8192 + (st * 16 + l15) * 64 + qkoff);
                    f32x4 z = {0.f, 0.f, 0.f, 0.f};
                    f32x4 s = __builtin_amdgcn_mfma_f32_16x16x32_bf16(kf, qf, z, 0, 0, 0);
                    float p0 = __builtin_amdgcn_exp2f(s[0]);
                    float p1 = __builtin_amdgcn_exp2f(s[1]);
                    float p2 = __builtin_amdgcn_exp2f(s[2]);
                    float p3 = __builtin_amdgcn_exp2f(s[3]);
                    if (st == tt) {  // diagonal tile: per-element causal mask
                        p0 = dmask[0] ? p0 : 0.f;
                        p1 = dmask[1] ? p1 : 0.f;
                        p2 = dmask[2] ? p2 : 0.f;
                        p3 = dmask[3] ? p3 : 0.f;
                    }
                    lac += (p0 + p1) + (p2 + p3);
                    int pp0 = (int)pk2(p0, p1), pp1 = (int)pk2(p2, p3);
                    short4v pf;
                    pf[0] = (short)(pp0 & 0xffff); pf[1] = (short)(pp0 >> 16);
                    pf[2] = (short)(pp1 & 0xffff); pf[3] = (short)(pp1 >> 16);
                    if (st & 1) o1 = MFMA16(vfrag[st], pf, o1);
                    else        o0 = MFMA16(vfrag[st], pf, o0);
                }
            }
            // row sum l(t): partials live at (l15=t, qd); fold quads
            float l = lac;
            l += __shfl_xor(l, 16, 64);
            l += __shfl_xor(l, 32, 64);
            float rl = __builtin_amdgcn_rcpf(l);
            if (qd < 2) {  // O^T rows d=qd*4+reg, only d<8 real
                float r0 = (o0[0] + o1[0]) * rl, r1 = (o0[1] + o1[1]) * rl;
                float r2 = (o0[2] + o1[2]) * rl, r3 = (o0[3] + o1[3]) * rl;
                int t = tt * 16 + l15;
                uint2 st2;
                st2.x = pk2(r0, r1);
                st2.y = pk2(r2, r3);
                *(uint2*)(ot + t * 64 + (((h * 2 + qd) ^ (l15 & 14)) << 2)) = st2;
            }
        }
    }
    __syncthreads();

    // ---------------- phase 3: out-projection via MFMA + bias + relu ----------------
    {
        const int tt = w;  // wave w owns t-tile w
        #pragma unroll
        for (int ot_ = 0; ot_ < 4; ++ot_) {
            f32x4 acc = {0.f, 0.f, 0.f, 0.f};
            const unsigned short* Ab = ws + 24576 + (ot_ * 16 + l15) * COUT + qd * 8;
            #pragma unroll
            for (int kc = 0; kc < 2; ++kc) {
                bf16x8 a = *(const bf16x8*)(Ab + kc * 32);
                bf16x8 bbv = *(const bf16x8*)(ot + (tt * 16 + l15) * 64
                                 + (((kc * 8 + qd * 2) ^ (l15 & 14)) << 2));
                acc = __builtin_amdgcn_mfma_f32_16x16x32_bf16(a, bbv, acc, 0, 0, 0);
            }
            int obase = ot_ * 16 + qd * 4;
            float4 bias = *(const float4*)(bo + obase);
            float bb4[4] = {bias.x, bias.y, bias.z, bias.w};
            int t = tt * 16 + l15;
            #pragma unroll
            for (int r = 0; r < 4; ++r) {
                float val = acc[r] + bb4[r];
                out[((b * COUT + obase + r) * Vv + v) * Tt + t] = val > 0.f ? val : 0.f;
            }
        }
    }
}

extern "C" void kernel_launch(void* const* d_in, const int* in_sizes, int n_in,
                              void* d_out, int out_size, void* d_ws, size_t ws_size,
                              hipStream_t stream) {
    (void)in_sizes; (void)n_in; (void)ws_size; (void)out_size;
    const float* x   = (const float*)d_in[0];
    const float* tem = (const float*)d_in[1];
    const float* Wq  = (const float*)d_in[2];
    const float* bq  = (const float*)d_in[3];
    const float* Wk  = (const float*)d_in[4];
    const float* bk  = (const float*)d_in[5];
    const float* Wv  = (const float*)d_in[6];
    const float* bv  = (const float*)d_in[7];
    const float* Wo  = (const float*)d_in[8];
    const float* bo  = (const float*)d_in[9];
    float* out = (float*)d_out;
    unsigned short* ws = (unsigned short*)d_ws;

    prep_w<<<dim3(112), dim3(256), 0, stream>>>(Wq, Wk, Wv, Wo, ws);
    tatt_fused<<<dim3(Bb * Vv), dim3(TPB), 0, stream>>>(
        x, tem, bq, bk, bv, bo, ws, out);
}